// Round 7
// baseline (571.598 us; speedup 1.0000x reference)
//
#include <hip/hip_runtime.h>
#include <hip/hip_bf16.h>

#define HN 16
#define DM 1024
#define DKH 64
#define BB 2
#define SS 2048
#define NT (BB*SS)   // 4096 tokens
#define BK 32        // GEMM K-step

using bf16   = __bf16;
using bf16x4 = __attribute__((ext_vector_type(4))) __bf16;
using bf16x8 = __attribute__((ext_vector_type(8))) __bf16;
using f32x4  = __attribute__((ext_vector_type(4))) float;

__device__ __forceinline__ void gload16(bf16* lds, const bf16* g) {
    __builtin_amdgcn_global_load_lds(
        (const __attribute__((address_space(1))) unsigned int*)g,
        (__attribute__((address_space(3))) unsigned int*)lds, 16, 0, 0);
}

// ---------------------------------------------------------------------------
// Prep: convert q,k,v (fp32) -> bf16 contiguous [3][NT][DM]
// ---------------------------------------------------------------------------
__global__ __launch_bounds__(256) void convert_qkv(
    const float* __restrict__ q, const float* __restrict__ k,
    const float* __restrict__ v, bf16* __restrict__ dst)
{
    const int z = blockIdx.z;
    const float* src = (z == 0) ? q : (z == 1) ? k : v;
    bf16* d = dst + (size_t)z * NT * DM;
    int i = blockIdx.x * 256 + threadIdx.x;
    const int n4 = NT * DM / 4;
    if (i < n4) {
        float4 f = ((const float4*)src)[i];
        bf16x4 o = { (bf16)f.x, (bf16)f.y, (bf16)f.z, (bf16)f.w };
        ((bf16x4*)d)[i] = o;
    }
}

// ---------------------------------------------------------------------------
// Prep: transpose 1024x1024 fp32 weights -> bf16 WT[n][k], 4 weights
// ---------------------------------------------------------------------------
__global__ __launch_bounds__(256) void transpose_w(
    const float* __restrict__ Wq, const float* __restrict__ Wk,
    const float* __restrict__ Wv, const float* __restrict__ Wp,
    bf16* __restrict__ dst)
{
    const int z = blockIdx.z;
    const float* W = (z == 0) ? Wq : (z == 1) ? Wk : (z == 2) ? Wv : Wp;
    bf16* WT = dst + (size_t)z * DM * DM;
    __shared__ float t[64][65];
    const int tx = threadIdx.x;
    const int r0 = blockIdx.y * 64, c0 = blockIdx.x * 64;
    {
        const int row = tx >> 2, cb = (tx & 3) * 16;
        const float4* src = (const float4*)(W + (size_t)(r0 + row) * DM + c0 + cb);
        #pragma unroll
        for (int i = 0; i < 4; i++) {
            float4 f = src[i];
            t[row][cb + i*4 + 0] = f.x; t[row][cb + i*4 + 1] = f.y;
            t[row][cb + i*4 + 2] = f.z; t[row][cb + i*4 + 3] = f.w;
        }
    }
    __syncthreads();
    {
        const int n = tx >> 2, kb = (tx & 3) * 16;
        bf16 buf[16];
        #pragma unroll
        for (int i = 0; i < 16; i++) buf[i] = (bf16)t[kb + i][n];
        bf16* outp = WT + (size_t)(c0 + n) * DM + r0 + kb;
        *(bf16x8*)(outp)     = *(bf16x8*)(&buf[0]);
        *(bf16x8*)(outp + 8) = *(bf16x8*)(&buf[8]);
    }
}

// ---------------------------------------------------------------------------
// 128x128x(K=1024) bf16 MFMA GEMM core, m97 structure.
// ---------------------------------------------------------------------------
__device__ __forceinline__ void gemm_core_128(
    const bf16* __restrict__ A, const bf16* __restrict__ Bt,
    int row0, int col0, bf16* As, bf16* Bs, f32x4 (&acc)[4][4])
{
    const int t = threadIdx.x;
    const int lane = t & 63, w = t >> 6;
    const int wr = w >> 1, wc = w & 1;
    const int lg = lane >> 4, l16 = lane & 15;
    const int srow = lane >> 2, scol = (lane & 3) * 8;
    const bf16* gA0 = A  + (size_t)(row0 + w*32 +      srow) * DM + scol;
    const bf16* gA1 = A  + (size_t)(row0 + w*32 + 16 + srow) * DM + scol;
    const bf16* gB0 = Bt + (size_t)(col0 + w*32 +      srow) * DM + scol;
    const bf16* gB1 = Bt + (size_t)(col0 + w*32 + 16 + srow) * DM + scol;
    bf16* lA0 = As + (w*32     ) * BK;
    bf16* lA1 = As + (w*32 + 16) * BK;
    bf16* lB0 = Bs + (w*32     ) * BK;
    bf16* lB1 = Bs + (w*32 + 16) * BK;

    for (int k0 = 0; k0 < DM; k0 += BK) {
        gload16(lA0, gA0 + k0);
        gload16(lA1, gA1 + k0);
        gload16(lB0, gB0 + k0);
        gload16(lB1, gB1 + k0);
        __syncthreads();
        bf16x8 af[4], bfr[4];
        #pragma unroll
        for (int m = 0; m < 4; m++)
            af[m] = *(const bf16x8*)(As + (wr*64 + m*16 + l16) * BK + lg*8);
        #pragma unroll
        for (int n = 0; n < 4; n++)
            bfr[n] = *(const bf16x8*)(Bs + (wc*64 + n*16 + l16) * BK + lg*8);
        #pragma unroll
        for (int m = 0; m < 4; m++)
            #pragma unroll
            for (int n = 0; n < 4; n++)
                acc[m][n] = __builtin_amdgcn_mfma_f32_16x16x32_bf16(af[m], bfr[n], acc[m][n], 0, 0, 0);
        __syncthreads();
    }
}

// ---------------------------------------------------------------------------
// QKV projection GEMM.
// z=0: Qh[B][H][S][DK] (pre-scaled by log2e/8)
// z=1: K in MFMA-fragment-swizzled layout
// z=2: V fragment-swizzled
// ---------------------------------------------------------------------------
__global__ __launch_bounds__(256) void gemm_qkv(
    const bf16* __restrict__ qkvb, const bf16* __restrict__ wT,
    const float* __restrict__ bq, const float* __restrict__ bk,
    const float* __restrict__ bv, bf16* __restrict__ outbase)
{
    __shared__ __align__(16) bf16 As[128 * BK];
    __shared__ __align__(16) bf16 Bs[128 * BK];
    const int z = blockIdx.z;
    const bf16* A;
    const bf16* Bt;
    int row0, col0;
    if (z != 2) {
        A    = qkvb + (size_t)z * NT * DM;
        Bt   = wT   + (size_t)z * DM * DM;
        row0 = blockIdx.y * 128;   // tokens
        col0 = blockIdx.x * 128;   // hdk
    } else {
        A    = wT   + (size_t)2 * DM * DM;   // rows = hdk
        Bt   = qkvb + (size_t)2 * NT * DM;   // rows = tokens
        row0 = blockIdx.x * 128;   // hdk
        col0 = blockIdx.y * 128;   // tokens
    }

    f32x4 acc[4][4] = {};
    gemm_core_128(A, Bt, row0, col0, As, Bs, acc);

    const int t = threadIdx.x, lane = t & 63, w = t >> 6;
    const int wr = w >> 1, wc = w & 1, lg = lane >> 4, l16 = lane & 15;

    if (z == 0) {
        bf16* outp = outbase;
        const float qscale = 0.125f * 1.44269504f;
        #pragma unroll
        for (int m = 0; m < 4; m++) {
            #pragma unroll
            for (int n = 0; n < 4; n++) {
                const int col = col0 + wc*64 + n*16 + l16;
                const float bcol = bq[col];
                const int h = col >> 6, dk = col & 63;
                #pragma unroll
                for (int r = 0; r < 4; r++) {
                    const int row = row0 + wr*64 + m*16 + lg*4 + r;
                    const int b = row >> 11, s = row & (SS - 1);
                    const float val = (acc[m][n][r] + bcol) * qscale;
                    outp[(((size_t)b*HN + h)*SS + s)*DKH + dk] = (bf16)val;
                }
            }
        }
    } else if (z == 1) {
        bf16* outp = outbase + (size_t)NT * DM;   // Kswz
        #pragma unroll
        for (int m = 0; m < 4; m++) {
            #pragma unroll
            for (int n = 0; n < 4; n++) {
                const int col = col0 + wc*64 + n*16 + l16;
                const float bcol = bk[col];
                const int h = col >> 6, d = col & 63;
                #pragma unroll
                for (int r = 0; r < 4; r++) {
                    const int row = row0 + wr*64 + m*16 + lg*4 + r;
                    const int b = row >> 11, s = row & (SS - 1);
                    const float val = acc[m][n][r] + bcol;
                    const size_t bh = (size_t)b*HN + h;
                    const size_t idx = bh*SS*DKH
                        + (size_t)(((s>>4)*2 + (d>>5))*512)
                        + ((s&15)*4 + ((d>>3)&3))*8 + (d&7);
                    outp[idx] = (bf16)val;
                }
            }
        }
    } else {
        bf16* outp = outbase + (size_t)2 * NT * DM;   // Vswz
        #pragma unroll
        for (int m = 0; m < 4; m++) {
            #pragma unroll
            for (int n = 0; n < 4; n++) {
                const int tok = col0 + wc*64 + n*16 + l16;
                const int b = tok >> 11, s = tok & (SS - 1);
                #pragma unroll
                for (int r = 0; r < 4; r++) {
                    const int hdk = row0 + wr*64 + m*16 + lg*4 + r;
                    const int h = hdk >> 6, dk = hdk & 63;
                    const float val = acc[m][n][r] + bv[hdk];
                    const size_t bh = (size_t)b*HN + h;
                    const size_t idx = bh*SS*DKH
                        + (size_t)(((s>>5)*4 + (dk>>4))*512)
                        + ((dk&15)*4 + ((s>>3)&3))*8 + (s&7);
                    outp[idx] = (bf16)val;
                }
            }
        }
    }
}

// ---------------------------------------------------------------------------
// Attention, fully-coalesced form (the 325us version). MEASUREMENT ROUND 2:
// runtime `reps` arg (host passes 2, opaque to compiler) loops the whole
// body so this dispatch (~480us) tops the duration-sorted counter table and
// exposes attn's own VGPR/Occupancy/MfmaUtil/VALUBusy/WRITE_SIZE/LDS rows
// for the first time. Body is byte-identical to the 325us baseline.
// ---------------------------------------------------------------------------
__global__ __launch_bounds__(256) void attn_kernel(
    const bf16* __restrict__ Qh, const bf16* __restrict__ Kswz,
    const bf16* __restrict__ Vswz, const int* __restrict__ mask,
    float* __restrict__ attn, bf16* __restrict__ Ob, int reps)
{
    __shared__ float bias_s[SS];                       // 8KB only
    const int hwid = blockIdx.x;                       // 0..511
    const int vid  = (hwid & 7) * 64 + (hwid >> 3);    // XCD-chunked
    const int bh = vid >> 4;
    const int b  = bh >> 4;
    const int q0 = (vid & 15) * 128;
    const bf16* Kb = Kswz + (size_t)bh * SS * DKH;
    const bf16* Vb = Vswz + (size_t)bh * SS * DKH;
    const bf16* Q  = Qh   + (size_t)bh * SS * DKH;
    const int t = threadIdx.x, w = t >> 6, lane = t & 63;
    const int lg = lane >> 4, l16 = lane & 15;
    const int lp = (l16 << 2) | lg;                    // fragment lane-perm

    for (int i = t; i < SS; i += 256)
        bias_s[i] = mask[b * SS + i] ? 0.0f : -1.44269504e9f;

    bf16x8 qf[2][2];
    #pragma unroll
    for (int tl = 0; tl < 2; tl++) {
        const bf16* qp = Q + (size_t)(q0 + w*32 + tl*16 + l16)*DKH + lg*8;
        qf[tl][0] = *(const bf16x8*)(qp);
        qf[tl][1] = *(const bf16x8*)(qp + 32);
    }
    __syncthreads();

    for (int rep = 0; rep < reps; rep++) {

    // ========== sweep 1: denominators (pure QK chain) ==========
    float l_[2] = {0.f, 0.f};
    bf16x8 kc0 = *(const bf16x8*)(Kb + lp*8);
    bf16x8 kc1 = *(const bf16x8*)(Kb + 512 + lp*8);
    for (int c = 0; c < 128; c++) {
        const int cn = (c + 1 < 128) ? c + 1 : 127;
        bf16x8 kn0 = *(const bf16x8*)(Kb + (size_t)(cn*2    )*512 + lp*8);
        bf16x8 kn1 = *(const bf16x8*)(Kb + (size_t)(cn*2 + 1)*512 + lp*8);
        const float4 b4 = *(const float4*)(&bias_s[c*16 + lg*4]);
        #pragma unroll
        for (int tl = 0; tl < 2; tl++) {
            f32x4 st = {0.f, 0.f, 0.f, 0.f};
            st = __builtin_amdgcn_mfma_f32_16x16x32_bf16(kc0, qf[tl][0], st, 0, 0, 0);
            st = __builtin_amdgcn_mfma_f32_16x16x32_bf16(kc1, qf[tl][1], st, 0, 0, 0);
            l_[tl] += exp2f(st[0] + b4.x) + exp2f(st[1] + b4.y)
                    + exp2f(st[2] + b4.z) + exp2f(st[3] + b4.w);
        }
        kc0 = kn0; kc1 = kn1;
    }
    float inv_l[2];
    #pragma unroll
    for (int tl = 0; tl < 2; tl++) {
        float l = l_[tl];
        l += __shfl_xor(l, 16);
        l += __shfl_xor(l, 32);
        inv_l[tl] = 1.0f / l;
    }

    // ========== sweep 2: recompute, PV, full-line attn stores ==========
    float* attn_base = attn + ((size_t)bh * SS + q0 + w*32) * SS;
    f32x4 oacc[2][4] = {};
    // bpermute source-lane byte indices (constants per lane)
    const int srcA = ((((2*lg)    ) & 3)*16 + l16) << 2;
    const int srcB = ((((2*lg) + 1) & 3)*16 + l16) << 2;
    const bool selT = (lg >= 2);              // pa tile select
    const int  kseg = lane & 7;               // store: k-segment
    const bool selS = (kseg >> 2) != 0;       // store tile select
    const int  srow8 = lane >> 3;             // store: row within 8
    const int srcS0 = ((kseg & 3)*16 +     srow8) << 2;
    const int srcS1 = ((kseg & 3)*16 + 8 + srow8) << 2;

    // prime K (tiles 0,1) and V (chunk 0)
    bf16x8 ck[4], cv[4];
    #pragma unroll
    for (int h = 0; h < 4; h++) ck[h] = *(const bf16x8*)(Kb + (size_t)h*512 + lp*8);
    #pragma unroll
    for (int n = 0; n < 4; n++) cv[n] = *(const bf16x8*)(Vb + (size_t)n*512 + lp*8);

    for (int j = 0; j < 64; j++) {
        bf16x8 nk[4], nv[4];
        const bool have = (j + 1) < 64;
        if (have) {
            #pragma unroll
            for (int h = 0; h < 4; h++)
                nk[h] = *(const bf16x8*)(Kb + (size_t)((j+1)*4 + h)*512 + lp*8);
            #pragma unroll
            for (int n = 0; n < 4; n++)
                nv[n] = *(const bf16x8*)(Vb + (size_t)((j+1)*4 + n)*512 + lp*8);
        }
        const float4 b40 = *(const float4*)(&bias_s[(2*j    )*16 + lg*4]);
        const float4 b41 = *(const float4*)(&bias_s[(2*j + 1)*16 + lg*4]);
        #pragma unroll
        for (int tl = 0; tl < 2; tl++) {
            f32x4 s0 = {0.f, 0.f, 0.f, 0.f};
            s0 = __builtin_amdgcn_mfma_f32_16x16x32_bf16(ck[0], qf[tl][0], s0, 0, 0, 0);
            s0 = __builtin_amdgcn_mfma_f32_16x16x32_bf16(ck[1], qf[tl][1], s0, 0, 0, 0);
            f32x4 s1 = {0.f, 0.f, 0.f, 0.f};
            s1 = __builtin_amdgcn_mfma_f32_16x16x32_bf16(ck[2], qf[tl][0], s1, 0, 0, 0);
            s1 = __builtin_amdgcn_mfma_f32_16x16x32_bf16(ck[3], qf[tl][1], s1, 0, 0, 0);
            const float p00 = exp2f(s0[0] + b40.x), p01 = exp2f(s0[1] + b40.y);
            const float p02 = exp2f(s0[2] + b40.z), p03 = exp2f(s0[3] + b40.w);
            const float p10 = exp2f(s1[0] + b41.x), p11 = exp2f(s1[1] + b41.y);
            const float p12 = exp2f(s1[2] + b41.z), p13 = exp2f(s1[3] + b41.w);
            // ---- PV A-fragment via bpermute (unnormalized bf16) ----
            bf16x4 pk0 = { (bf16)p00, (bf16)p01, (bf16)p02, (bf16)p03 };
            bf16x4 pk1 = { (bf16)p10, (bf16)p11, (bf16)p12, (bf16)p13 };
            int2 k0d = *(int2*)&pk0;
            int2 k1d = *(int2*)&pk1;
            int dd0t0 = __builtin_amdgcn_ds_bpermute(srcA, k0d.x);
            int dd0t1 = __builtin_amdgcn_ds_bpermute(srcA, k1d.x);
            int dd1t0 = __builtin_amdgcn_ds_bpermute(srcA, k0d.y);
            int dd1t1 = __builtin_amdgcn_ds_bpermute(srcA, k1d.y);
            int dd2t0 = __builtin_amdgcn_ds_bpermute(srcB, k0d.x);
            int dd2t1 = __builtin_amdgcn_ds_bpermute(srcB, k1d.x);
            int dd3t0 = __builtin_amdgcn_ds_bpermute(srcB, k0d.y);
            int dd3t1 = __builtin_amdgcn_ds_bpermute(srcB, k1d.y);
            union { int4 i; bf16x8 h; } pa;
            pa.i.x = selT ? dd0t1 : dd0t0;
            pa.i.y = selT ? dd1t1 : dd1t0;
            pa.i.z = selT ? dd2t1 : dd2t0;
            pa.i.w = selT ? dd3t1 : dd3t0;
            #pragma unroll
            for (int n = 0; n < 4; n++)
                oacc[tl][n] = __builtin_amdgcn_mfma_f32_16x16x32_bf16(pa.h, cv[n], oacc[tl][n], 0, 0, 0);
            // ---- full-line attn stores via bpermute transpose ----
            const float il = inv_l[tl];
            f32x4 pv0 = { p00*il, p01*il, p02*il, p03*il };
            f32x4 pv1 = { p10*il, p11*il, p12*il, p13*il };
            #pragma unroll
            for (int i = 0; i < 2; i++) {
                const int srcS = i ? srcS1 : srcS0;
                f32x4 outv;
                #pragma unroll
                for (int d = 0; d < 4; d++) {
                    int v0 = __builtin_amdgcn_ds_bpermute(srcS, __float_as_int(pv0[d]));
                    int v1 = __builtin_amdgcn_ds_bpermute(srcS, __float_as_int(pv1[d]));
                    outv[d] = __int_as_float(selS ? v1 : v0);
                }
                *(f32x4*)(attn_base + (size_t)(tl*16 + i*8 + srow8)*SS + j*32 + kseg*4) = outv;
            }
        }
        #pragma unroll
        for (int h = 0; h < 4; h++) ck[h] = nk[h];
        #pragma unroll
        for (int n = 0; n < 4; n++) cv[n] = nv[n];
    }

    // ---- epilogue: O * inv_l -> Ob ----
    const int hh = bh & 15;
    #pragma unroll
    for (int tl = 0; tl < 2; tl++) {
        #pragma unroll
        for (int r = 0; r < 4; r++) {
            const float il = __shfl(inv_l[tl], lg*4 + r);
            const int srow = q0 + w*32 + tl*16 + lg*4 + r;
            #pragma unroll
            for (int n = 0; n < 4; n++) {
                const float val = oacc[tl][n][r] * il;
                Ob[((size_t)b*SS + srow)*DM + hh*DKH + n*16 + l16] = (bf16)val;
            }
        }
    }

    }  // rep
}

// ---------------------------------------------------------------------------
// Output projection + bias + residual -> fp32 x (pre-LN) into d_out
// ---------------------------------------------------------------------------
__global__ __launch_bounds__(256) void gemm_out(
    const bf16* __restrict__ Ob, const bf16* __restrict__ WpT,
    const float* __restrict__ bp, const float* __restrict__ resid,
    float* __restrict__ out)
{
    __shared__ __align__(16) bf16 As[128 * BK];
    __shared__ __align__(16) bf16 Bs[128 * BK];
    const int row0 = blockIdx.y * 128, col0 = blockIdx.x * 128;
    f32x4 acc[4][4] = {};
    gemm_core_128(Ob, WpT, row0, col0, As, Bs, acc);

    const int t = threadIdx.x, lane = t & 63, w = t >> 6;
    const int wr = w >> 1, wc = w & 1, lg = lane >> 4, l16 = lane & 15;
    #pragma unroll
    for (int m = 0; m < 4; m++) {
        #pragma unroll
        for (int n = 0; n < 4; n++) {
            const int col = col0 + wc*64 + n*16 + l16;
            const float bcol = bp[col];
            #pragma unroll
            for (int r = 0; r < 4; r++) {
                const int row = row0 + wr*64 + m*16 + lg*4 + r;
                const size_t idx = (size_t)row * DM + col;
                out[idx] = acc[m][n][r] + bcol + resid[idx];
            }
        }
    }
}

// ---------------------------------------------------------------------------
// In-place LayerNorm over last dim (1024), one block per token row
// ---------------------------------------------------------------------------
__global__ __launch_bounds__(256) void ln_kernel(
    float* __restrict__ x, const float* __restrict__ gamma,
    const float* __restrict__ beta)
{
    const int row = blockIdx.x, t = threadIdx.x;
    float4 v = ((const float4*)(x + (size_t)row * DM))[t];
    float s  = v.x + v.y + v.z + v.w;
    float s2 = v.x*v.x + v.y*v.y + v.z*v.z + v.w*v.w;
    #pragma unroll
    for (int off = 32; off; off >>= 1) {
        s  += __shfl_xor(s, off);
        s2 += __shfl_xor(s2, off);
    }
    __shared__ float rs_[4], rs2_[4];
    const int w = t >> 6;
    if ((t & 63) == 0) { rs_[w] = s; rs2_[w] = s2; }
    __syncthreads();
    s  = rs_[0] + rs_[1] + rs_[2] + rs_[3];
    s2 = rs2_[0] + rs2_[1] + rs2_[2] + rs2_[3];
    const float mu   = s * (1.0f / DM);
    const float var  = s2 * (1.0f / DM) - mu * mu;
    const float rstd = rsqrtf(var + 1e-5f);
    float4 g  = ((const float4*)gamma)[t];
    float4 bb = ((const float4*)beta)[t];
    float4 o;
    o.x = (v.x - mu) * rstd * g.x + bb.x;
    o.y = (v.y - mu) * rstd * g.y + bb.y;
    o.z = (v.z - mu) * rstd * g.z + bb.z;
    o.w = (v.w - mu) * rstd * g.w + bb.w;
    ((float4*)(x + (size_t)row * DM))[t] = o;
}

// ---------------------------------------------------------------------------
extern "C" void kernel_launch(void* const* d_in, const int* in_sizes, int n_in,
                              void* d_out, int out_size, void* d_ws, size_t ws_size,
                              hipStream_t stream)
{
    const float* q     = (const float*)d_in[0];
    const float* k     = (const float*)d_in[1];
    const float* v     = (const float*)d_in[2];
    const int*   mask  = (const int*)  d_in[3];
    const float* Wq    = (const float*)d_in[4];
    const float* bq    = (const float*)d_in[5];
    const float* Wk    = (const float*)d_in[6];
    const float* bk    = (const float*)d_in[7];
    const float* Wv    = (const float*)d_in[8];
    const float* bv    = (const float*)d_in[9];
    const float* Wp    = (const float*)d_in[10];
    const float* bp    = (const float*)d_in[11];
    const float* gamma = (const float*)d_in[12];
    const float* beta  = (const float*)d_in[13];

    float* out  = (float*)d_out;
    float* attn = out + (size_t)NT * DM;

    char* wsb = (char*)d_ws;
    bf16* qb   = (bf16*)wsb;                    //  0MB: q,k,v bf16 (3x8MB)
    bf16* wT   = (bf16*)(wsb + 25165824);       // 24MB: WqT,WkT,WvT,WpT bf16
    bf16* Qh   = (bf16*)(wsb + 33554432);       // 32MB: Qh (pre-scaled), then Kswz(40MB), Vswz(48MB)
    bf16* Ob   = (bf16*)(wsb + 58720256);       // 56MB: attn-out bf16 [B][S][DM]
    bf16* Kswz = Qh + (size_t)NT * DM;
    bf16* Vswz = Qh + (size_t)2 * NT * DM;

    convert_qkv<<<dim3(4096, 1, 3), 256, 0, stream>>>(q, k, v, qb);
    transpose_w<<<dim3(16, 16, 4), 256, 0, stream>>>(Wq, Wk, Wv, Wp, wT);
    gemm_qkv   <<<dim3(8, 32, 3),  256, 0, stream>>>(qb, wT, bq, bk, bv, Qh);
    // MEASUREMENT: reps=2 (runtime arg) -> this dispatch ~480us, top of the
    // duration-sorted rocprof table -> first real counter row for attn.
    attn_kernel<<<dim3(512, 1),    256, 0, stream>>>(Qh, Kswz, Vswz, mask, attn, Ob, 2);
    gemm_out   <<<dim3(8, 32),     256, 0, stream>>>(Ob, wT + 3*1048576, bp, q, out);
    ln_kernel  <<<4096,            256, 0, stream>>>(out, gamma, beta);
}

// Round 8
// 328.848 us; speedup vs baseline: 1.7382x; 1.7382x over previous
//
#include <hip/hip_runtime.h>
#include <hip/hip_bf16.h>

#define HN 16
#define DM 1024
#define DKH 64
#define BB 2
#define SS 2048
#define NT (BB*SS)   // 4096 tokens
#define BK 32        // GEMM K-step

using bf16   = __bf16;
using bf16x4 = __attribute__((ext_vector_type(4))) __bf16;
using bf16x8 = __attribute__((ext_vector_type(8))) __bf16;
using f32x4  = __attribute__((ext_vector_type(4))) float;

#define EXP2 __builtin_amdgcn_exp2f

__device__ __forceinline__ void gload16(bf16* lds, const bf16* g) {
    __builtin_amdgcn_global_load_lds(
        (const __attribute__((address_space(1))) unsigned int*)g,
        (__attribute__((address_space(3))) unsigned int*)lds, 16, 0, 0);
}

// ---------------------------------------------------------------------------
// Prep: convert q,k,v (fp32) -> bf16 contiguous [3][NT][DM]
// ---------------------------------------------------------------------------
__global__ __launch_bounds__(256) void convert_qkv(
    const float* __restrict__ q, const float* __restrict__ k,
    const float* __restrict__ v, bf16* __restrict__ dst)
{
    const int z = blockIdx.z;
    const float* src = (z == 0) ? q : (z == 1) ? k : v;
    bf16* d = dst + (size_t)z * NT * DM;
    int i = blockIdx.x * 256 + threadIdx.x;
    const int n4 = NT * DM / 4;
    if (i < n4) {
        float4 f = ((const float4*)src)[i];
        bf16x4 o = { (bf16)f.x, (bf16)f.y, (bf16)f.z, (bf16)f.w };
        ((bf16x4*)d)[i] = o;
    }
}

// ---------------------------------------------------------------------------
// Prep: transpose 1024x1024 fp32 weights -> bf16 WT[n][k], 4 weights
// ---------------------------------------------------------------------------
__global__ __launch_bounds__(256) void transpose_w(
    const float* __restrict__ Wq, const float* __restrict__ Wk,
    const float* __restrict__ Wv, const float* __restrict__ Wp,
    bf16* __restrict__ dst)
{
    const int z = blockIdx.z;
    const float* W = (z == 0) ? Wq : (z == 1) ? Wk : (z == 2) ? Wv : Wp;
    bf16* WT = dst + (size_t)z * DM * DM;
    __shared__ float t[64][65];
    const int tx = threadIdx.x;
    const int r0 = blockIdx.y * 64, c0 = blockIdx.x * 64;
    {
        const int row = tx >> 2, cb = (tx & 3) * 16;
        const float4* src = (const float4*)(W + (size_t)(r0 + row) * DM + c0 + cb);
        #pragma unroll
        for (int i = 0; i < 4; i++) {
            float4 f = src[i];
            t[row][cb + i*4 + 0] = f.x; t[row][cb + i*4 + 1] = f.y;
            t[row][cb + i*4 + 2] = f.z; t[row][cb + i*4 + 3] = f.w;
        }
    }
    __syncthreads();
    {
        const int n = tx >> 2, kb = (tx & 3) * 16;
        bf16 buf[16];
        #pragma unroll
        for (int i = 0; i < 16; i++) buf[i] = (bf16)t[kb + i][n];
        bf16* outp = WT + (size_t)(c0 + n) * DM + r0 + kb;
        *(bf16x8*)(outp)     = *(bf16x8*)(&buf[0]);
        *(bf16x8*)(outp + 8) = *(bf16x8*)(&buf[8]);
    }
}

// ---------------------------------------------------------------------------
// 128x128x(K=1024) bf16 MFMA GEMM core, m97 structure.
// ---------------------------------------------------------------------------
__device__ __forceinline__ void gemm_core_128(
    const bf16* __restrict__ A, const bf16* __restrict__ Bt,
    int row0, int col0, bf16* As, bf16* Bs, f32x4 (&acc)[4][4])
{
    const int t = threadIdx.x;
    const int lane = t & 63, w = t >> 6;
    const int wr = w >> 1, wc = w & 1;
    const int lg = lane >> 4, l16 = lane & 15;
    const int srow = lane >> 2, scol = (lane & 3) * 8;
    const bf16* gA0 = A  + (size_t)(row0 + w*32 +      srow) * DM + scol;
    const bf16* gA1 = A  + (size_t)(row0 + w*32 + 16 + srow) * DM + scol;
    const bf16* gB0 = Bt + (size_t)(col0 + w*32 +      srow) * DM + scol;
    const bf16* gB1 = Bt + (size_t)(col0 + w*32 + 16 + srow) * DM + scol;
    bf16* lA0 = As + (w*32     ) * BK;
    bf16* lA1 = As + (w*32 + 16) * BK;
    bf16* lB0 = Bs + (w*32     ) * BK;
    bf16* lB1 = Bs + (w*32 + 16) * BK;

    for (int k0 = 0; k0 < DM; k0 += BK) {
        gload16(lA0, gA0 + k0);
        gload16(lA1, gA1 + k0);
        gload16(lB0, gB0 + k0);
        gload16(lB1, gB1 + k0);
        __syncthreads();
        bf16x8 af[4], bfr[4];
        #pragma unroll
        for (int m = 0; m < 4; m++)
            af[m] = *(const bf16x8*)(As + (wr*64 + m*16 + l16) * BK + lg*8);
        #pragma unroll
        for (int n = 0; n < 4; n++)
            bfr[n] = *(const bf16x8*)(Bs + (wc*64 + n*16 + l16) * BK + lg*8);
        #pragma unroll
        for (int m = 0; m < 4; m++)
            #pragma unroll
            for (int n = 0; n < 4; n++)
                acc[m][n] = __builtin_amdgcn_mfma_f32_16x16x32_bf16(af[m], bfr[n], acc[m][n], 0, 0, 0);
        __syncthreads();
    }
}

// ---------------------------------------------------------------------------
// QKV projection GEMM.
// z=0: Qh[B][H][S][DK] (pre-scaled by log2e/8)
// z=1: K in MFMA-fragment-swizzled layout
// z=2: V fragment-swizzled
// ---------------------------------------------------------------------------
__global__ __launch_bounds__(256) void gemm_qkv(
    const bf16* __restrict__ qkvb, const bf16* __restrict__ wT,
    const float* __restrict__ bq, const float* __restrict__ bk,
    const float* __restrict__ bv, bf16* __restrict__ outbase)
{
    __shared__ __align__(16) bf16 As[128 * BK];
    __shared__ __align__(16) bf16 Bs[128 * BK];
    const int z = blockIdx.z;
    const bf16* A;
    const bf16* Bt;
    int row0, col0;
    if (z != 2) {
        A    = qkvb + (size_t)z * NT * DM;
        Bt   = wT   + (size_t)z * DM * DM;
        row0 = blockIdx.y * 128;   // tokens
        col0 = blockIdx.x * 128;   // hdk
    } else {
        A    = wT   + (size_t)2 * DM * DM;   // rows = hdk
        Bt   = qkvb + (size_t)2 * NT * DM;   // rows = tokens
        row0 = blockIdx.x * 128;   // hdk
        col0 = blockIdx.y * 128;   // tokens
    }

    f32x4 acc[4][4] = {};
    gemm_core_128(A, Bt, row0, col0, As, Bs, acc);

    const int t = threadIdx.x, lane = t & 63, w = t >> 6;
    const int wr = w >> 1, wc = w & 1, lg = lane >> 4, l16 = lane & 15;

    if (z == 0) {
        bf16* outp = outbase;
        const float qscale = 0.125f * 1.44269504f;
        #pragma unroll
        for (int m = 0; m < 4; m++) {
            #pragma unroll
            for (int n = 0; n < 4; n++) {
                const int col = col0 + wc*64 + n*16 + l16;
                const float bcol = bq[col];
                const int h = col >> 6, dk = col & 63;
                #pragma unroll
                for (int r = 0; r < 4; r++) {
                    const int row = row0 + wr*64 + m*16 + lg*4 + r;
                    const int b = row >> 11, s = row & (SS - 1);
                    const float val = (acc[m][n][r] + bcol) * qscale;
                    outp[(((size_t)b*HN + h)*SS + s)*DKH + dk] = (bf16)val;
                }
            }
        }
    } else if (z == 1) {
        bf16* outp = outbase + (size_t)NT * DM;   // Kswz
        #pragma unroll
        for (int m = 0; m < 4; m++) {
            #pragma unroll
            for (int n = 0; n < 4; n++) {
                const int col = col0 + wc*64 + n*16 + l16;
                const float bcol = bk[col];
                const int h = col >> 6, d = col & 63;
                #pragma unroll
                for (int r = 0; r < 4; r++) {
                    const int row = row0 + wr*64 + m*16 + lg*4 + r;
                    const int b = row >> 11, s = row & (SS - 1);
                    const float val = acc[m][n][r] + bcol;
                    const size_t bh = (size_t)b*HN + h;
                    const size_t idx = bh*SS*DKH
                        + (size_t)(((s>>4)*2 + (d>>5))*512)
                        + ((s&15)*4 + ((d>>3)&3))*8 + (d&7);
                    outp[idx] = (bf16)val;
                }
            }
        }
    } else {
        bf16* outp = outbase + (size_t)2 * NT * DM;   // Vswz
        #pragma unroll
        for (int m = 0; m < 4; m++) {
            #pragma unroll
            for (int n = 0; n < 4; n++) {
                const int tok = col0 + wc*64 + n*16 + l16;
                const int b = tok >> 11, s = tok & (SS - 1);
                #pragma unroll
                for (int r = 0; r < 4; r++) {
                    const int hdk = row0 + wr*64 + m*16 + lg*4 + r;
                    const int h = hdk >> 6, dk = hdk & 63;
                    const float val = acc[m][n][r] + bv[hdk];
                    const size_t bh = (size_t)b*HN + h;
                    const size_t idx = bh*SS*DKH
                        + (size_t)(((s>>5)*4 + (dk>>4))*512)
                        + ((dk&15)*4 + ((s>>3)&3))*8 + (s&7);
                    outp[idx] = (bf16)val;
                }
            }
        }
    }
}

// ---------------------------------------------------------------------------
// Attention, VALU-slimmed form of the 325us kernel. R7 counters: VALUBusy
// 44.6% (top pipe), MfmaUtil 9%, HBM 30% -> VALU instruction count is the
// largest term. Three VALU cuts, zero structural change:
//  1. exp2f -> raw v_exp_f32 (library call was ~6 instrs; masked lanes:
//     v_exp_f32(-1.4e9) = 0, exact).
//  2. bias folded into MFMA C-init (hardware does the adds).
//  3. log2(inv_l) folded into sweep-2 C-init -> P emerges NORMALIZED:
//     deletes il muls + epilogue rescale; PV consumes normalized P.
// bpermutes, stores, prefetch, layouts: byte-identical to baseline.
// ---------------------------------------------------------------------------
__global__ __launch_bounds__(256) void attn_kernel(
    const bf16* __restrict__ Qh, const bf16* __restrict__ Kswz,
    const bf16* __restrict__ Vswz, const int* __restrict__ mask,
    float* __restrict__ attn, bf16* __restrict__ Ob)
{
    __shared__ float bias_s[SS];                       // 8KB only
    const int hwid = blockIdx.x;                       // 0..511
    const int vid  = (hwid & 7) * 64 + (hwid >> 3);    // XCD-chunked
    const int bh = vid >> 4;
    const int b  = bh >> 4;
    const int q0 = (vid & 15) * 128;
    const bf16* Kb = Kswz + (size_t)bh * SS * DKH;
    const bf16* Vb = Vswz + (size_t)bh * SS * DKH;
    const bf16* Q  = Qh   + (size_t)bh * SS * DKH;
    const int t = threadIdx.x, w = t >> 6, lane = t & 63;
    const int lg = lane >> 4, l16 = lane & 15;
    const int lp = (l16 << 2) | lg;                    // fragment lane-perm

    for (int i = t; i < SS; i += 256)
        bias_s[i] = mask[b * SS + i] ? 0.0f : -1.44269504e9f;

    bf16x8 qf[2][2];
    #pragma unroll
    for (int tl = 0; tl < 2; tl++) {
        const bf16* qp = Q + (size_t)(q0 + w*32 + tl*16 + l16)*DKH + lg*8;
        qf[tl][0] = *(const bf16x8*)(qp);
        qf[tl][1] = *(const bf16x8*)(qp + 32);
    }
    __syncthreads();

    // ========== sweep 1: denominators (bias as MFMA C-init, raw exp) =====
    float l_[2] = {0.f, 0.f};
    bf16x8 kc0 = *(const bf16x8*)(Kb + lp*8);
    bf16x8 kc1 = *(const bf16x8*)(Kb + 512 + lp*8);
    for (int c = 0; c < 128; c++) {
        const int cn = (c + 1 < 128) ? c + 1 : 127;
        bf16x8 kn0 = *(const bf16x8*)(Kb + (size_t)(cn*2    )*512 + lp*8);
        bf16x8 kn1 = *(const bf16x8*)(Kb + (size_t)(cn*2 + 1)*512 + lp*8);
        const float4 b4 = *(const float4*)(&bias_s[c*16 + lg*4]);
        #pragma unroll
        for (int tl = 0; tl < 2; tl++) {
            f32x4 st = {b4.x, b4.y, b4.z, b4.w};
            st = __builtin_amdgcn_mfma_f32_16x16x32_bf16(kc0, qf[tl][0], st, 0, 0, 0);
            st = __builtin_amdgcn_mfma_f32_16x16x32_bf16(kc1, qf[tl][1], st, 0, 0, 0);
            l_[tl] += EXP2(st[0]) + EXP2(st[1]) + EXP2(st[2]) + EXP2(st[3]);
        }
        kc0 = kn0; kc1 = kn1;
    }
    float il_log[2];
    #pragma unroll
    for (int tl = 0; tl < 2; tl++) {
        float l = l_[tl];
        l += __shfl_xor(l, 16);
        l += __shfl_xor(l, 32);
        il_log[tl] = -log2f(l);        // log2(1/l), folded into sweep-2 C-init
    }

    // ========== sweep 2: recompute (normalized), PV, full-line stores =====
    float* attn_base = attn + ((size_t)bh * SS + q0 + w*32) * SS;
    f32x4 oacc[2][4] = {};
    // bpermute source-lane byte indices (constants per lane)
    const int srcA = ((((2*lg)    ) & 3)*16 + l16) << 2;
    const int srcB = ((((2*lg) + 1) & 3)*16 + l16) << 2;
    const bool selT = (lg >= 2);              // pa tile select
    const int  kseg = lane & 7;               // store: k-segment
    const bool selS = (kseg >> 2) != 0;       // store tile select
    const int  srow8 = lane >> 3;             // store: row within 8
    const int srcS0 = ((kseg & 3)*16 +     srow8) << 2;
    const int srcS1 = ((kseg & 3)*16 + 8 + srow8) << 2;

    // prime K (tiles 0,1) and V (chunk 0)
    bf16x8 ck[4], cv[4];
    #pragma unroll
    for (int h = 0; h < 4; h++) ck[h] = *(const bf16x8*)(Kb + (size_t)h*512 + lp*8);
    #pragma unroll
    for (int n = 0; n < 4; n++) cv[n] = *(const bf16x8*)(Vb + (size_t)n*512 + lp*8);

    for (int j = 0; j < 64; j++) {
        bf16x8 nk[4], nv[4];
        const bool have = (j + 1) < 64;
        if (have) {
            #pragma unroll
            for (int h = 0; h < 4; h++)
                nk[h] = *(const bf16x8*)(Kb + (size_t)((j+1)*4 + h)*512 + lp*8);
            #pragma unroll
            for (int n = 0; n < 4; n++)
                nv[n] = *(const bf16x8*)(Vb + (size_t)((j+1)*4 + n)*512 + lp*8);
        }
        const float4 b40 = *(const float4*)(&bias_s[(2*j    )*16 + lg*4]);
        const float4 b41 = *(const float4*)(&bias_s[(2*j + 1)*16 + lg*4]);
        #pragma unroll
        for (int tl = 0; tl < 2; tl++) {
            const float il2 = il_log[tl];
            f32x4 s0 = {b40.x + il2, b40.y + il2, b40.z + il2, b40.w + il2};
            s0 = __builtin_amdgcn_mfma_f32_16x16x32_bf16(ck[0], qf[tl][0], s0, 0, 0, 0);
            s0 = __builtin_amdgcn_mfma_f32_16x16x32_bf16(ck[1], qf[tl][1], s0, 0, 0, 0);
            f32x4 s1 = {b41.x + il2, b41.y + il2, b41.z + il2, b41.w + il2};
            s1 = __builtin_amdgcn_mfma_f32_16x16x32_bf16(ck[2], qf[tl][0], s1, 0, 0, 0);
            s1 = __builtin_amdgcn_mfma_f32_16x16x32_bf16(ck[3], qf[tl][1], s1, 0, 0, 0);
            const float p00 = EXP2(s0[0]), p01 = EXP2(s0[1]);
            const float p02 = EXP2(s0[2]), p03 = EXP2(s0[3]);
            const float p10 = EXP2(s1[0]), p11 = EXP2(s1[1]);
            const float p12 = EXP2(s1[2]), p13 = EXP2(s1[3]);
            // ---- PV A-fragment via bpermute (normalized bf16) ----
            bf16x4 pk0 = { (bf16)p00, (bf16)p01, (bf16)p02, (bf16)p03 };
            bf16x4 pk1 = { (bf16)p10, (bf16)p11, (bf16)p12, (bf16)p13 };
            int2 k0d = *(int2*)&pk0;
            int2 k1d = *(int2*)&pk1;
            int dd0t0 = __builtin_amdgcn_ds_bpermute(srcA, k0d.x);
            int dd0t1 = __builtin_amdgcn_ds_bpermute(srcA, k1d.x);
            int dd1t0 = __builtin_amdgcn_ds_bpermute(srcA, k0d.y);
            int dd1t1 = __builtin_amdgcn_ds_bpermute(srcA, k1d.y);
            int dd2t0 = __builtin_amdgcn_ds_bpermute(srcB, k0d.x);
            int dd2t1 = __builtin_amdgcn_ds_bpermute(srcB, k1d.x);
            int dd3t0 = __builtin_amdgcn_ds_bpermute(srcB, k0d.y);
            int dd3t1 = __builtin_amdgcn_ds_bpermute(srcB, k1d.y);
            union { int4 i; bf16x8 h; } pa;
            pa.i.x = selT ? dd0t1 : dd0t0;
            pa.i.y = selT ? dd1t1 : dd1t0;
            pa.i.z = selT ? dd2t1 : dd2t0;
            pa.i.w = selT ? dd3t1 : dd3t0;
            #pragma unroll
            for (int n = 0; n < 4; n++)
                oacc[tl][n] = __builtin_amdgcn_mfma_f32_16x16x32_bf16(pa.h, cv[n], oacc[tl][n], 0, 0, 0);
            // ---- full-line attn stores via bpermute transpose ----
            f32x4 pv0 = { p00, p01, p02, p03 };
            f32x4 pv1 = { p10, p11, p12, p13 };
            #pragma unroll
            for (int i = 0; i < 2; i++) {
                const int srcS = i ? srcS1 : srcS0;
                f32x4 outv;
                #pragma unroll
                for (int d = 0; d < 4; d++) {
                    int v0 = __builtin_amdgcn_ds_bpermute(srcS, __float_as_int(pv0[d]));
                    int v1 = __builtin_amdgcn_ds_bpermute(srcS, __float_as_int(pv1[d]));
                    outv[d] = __int_as_float(selS ? v1 : v0);
                }
                *(f32x4*)(attn_base + (size_t)(tl*16 + i*8 + srow8)*SS + j*32 + kseg*4) = outv;
            }
        }
        #pragma unroll
        for (int h = 0; h < 4; h++) ck[h] = nk[h];
        #pragma unroll
        for (int n = 0; n < 4; n++) cv[n] = nv[n];
    }

    // ---- epilogue: O already normalized -> Ob ----
    const int hh = bh & 15;
    #pragma unroll
    for (int tl = 0; tl < 2; tl++) {
        #pragma unroll
        for (int r = 0; r < 4; r++) {
            const int srow = q0 + w*32 + tl*16 + lg*4 + r;
            #pragma unroll
            for (int n = 0; n < 4; n++) {
                const float val = oacc[tl][n][r];
                Ob[((size_t)b*SS + srow)*DM + hh*DKH + n*16 + l16] = (bf16)val;
            }
        }
    }
}

// ---------------------------------------------------------------------------
// Output projection + bias + residual -> fp32 x (pre-LN) into d_out
// ---------------------------------------------------------------------------
__global__ __launch_bounds__(256) void gemm_out(
    const bf16* __restrict__ Ob, const bf16* __restrict__ WpT,
    const float* __restrict__ bp, const float* __restrict__ resid,
    float* __restrict__ out)
{
    __shared__ __align__(16) bf16 As[128 * BK];
    __shared__ __align__(16) bf16 Bs[128 * BK];
    const int row0 = blockIdx.y * 128, col0 = blockIdx.x * 128;
    f32x4 acc[4][4] = {};
    gemm_core_128(Ob, WpT, row0, col0, As, Bs, acc);

    const int t = threadIdx.x, lane = t & 63, w = t >> 6;
    const int wr = w >> 1, wc = w & 1, lg = lane >> 4, l16 = lane & 15;
    #pragma unroll
    for (int m = 0; m < 4; m++) {
        #pragma unroll
        for (int n = 0; n < 4; n++) {
            const int col = col0 + wc*64 + n*16 + l16;
            const float bcol = bp[col];
            #pragma unroll
            for (int r = 0; r < 4; r++) {
                const int row = row0 + wr*64 + m*16 + lg*4 + r;
                const size_t idx = (size_t)row * DM + col;
                out[idx] = acc[m][n][r] + bcol + resid[idx];
            }
        }
    }
}

// ---------------------------------------------------------------------------
// In-place LayerNorm over last dim (1024), one block per token row
// ---------------------------------------------------------------------------
__global__ __launch_bounds__(256) void ln_kernel(
    float* __restrict__ x, const float* __restrict__ gamma,
    const float* __restrict__ beta)
{
    const int row = blockIdx.x, t = threadIdx.x;
    float4 v = ((const float4*)(x + (size_t)row * DM))[t];
    float s  = v.x + v.y + v.z + v.w;
    float s2 = v.x*v.x + v.y*v.y + v.z*v.z + v.w*v.w;
    #pragma unroll
    for (int off = 32; off; off >>= 1) {
        s  += __shfl_xor(s, off);
        s2 += __shfl_xor(s2, off);
    }
    __shared__ float rs_[4], rs2_[4];
    const int w = t >> 6;
    if ((t & 63) == 0) { rs_[w] = s; rs2_[w] = s2; }
    __syncthreads();
    s  = rs_[0] + rs_[1] + rs_[2] + rs_[3];
    s2 = rs2_[0] + rs2_[1] + rs2_[2] + rs2_[3];
    const float mu   = s * (1.0f / DM);
    const float var  = s2 * (1.0f / DM) - mu * mu;
    const float rstd = rsqrtf(var + 1e-5f);
    float4 g  = ((const float4*)gamma)[t];
    float4 bb = ((const float4*)beta)[t];
    float4 o;
    o.x = (v.x - mu) * rstd * g.x + bb.x;
    o.y = (v.y - mu) * rstd * g.y + bb.y;
    o.z = (v.z - mu) * rstd * g.z + bb.z;
    o.w = (v.w - mu) * rstd * g.w + bb.w;
    ((float4*)(x + (size_t)row * DM))[t] = o;
}

// ---------------------------------------------------------------------------
extern "C" void kernel_launch(void* const* d_in, const int* in_sizes, int n_in,
                              void* d_out, int out_size, void* d_ws, size_t ws_size,
                              hipStream_t stream)
{
    const float* q     = (const float*)d_in[0];
    const float* k     = (const float*)d_in[1];
    const float* v     = (const float*)d_in[2];
    const int*   mask  = (const int*)  d_in[3];
    const float* Wq    = (const float*)d_in[4];
    const float* bq    = (const float*)d_in[5];
    const float* Wk    = (const float*)d_in[6];
    const float* bk    = (const float*)d_in[7];
    const float* Wv    = (const float*)d_in[8];
    const float* bv    = (const float*)d_in[9];
    const float* Wp    = (const float*)d_in[10];
    const float* bp    = (const float*)d_in[11];
    const float* gamma = (const float*)d_in[12];
    const float* beta  = (const float*)d_in[13];

    float* out  = (float*)d_out;
    float* attn = out + (size_t)NT * DM;

    char* wsb = (char*)d_ws;
    bf16* qb   = (bf16*)wsb;                    //  0MB: q,k,v bf16 (3x8MB)
    bf16* wT   = (bf16*)(wsb + 25165824);       // 24MB: WqT,WkT,WvT,WpT bf16
    bf16* Qh   = (bf16*)(wsb + 33554432);       // 32MB: Qh (pre-scaled), then Kswz(40MB), Vswz(48MB)
    bf16* Ob   = (bf16*)(wsb + 58720256);       // 56MB: attn-out bf16 [B][S][DM]
    bf16* Kswz = Qh + (size_t)NT * DM;
    bf16* Vswz = Qh + (size_t)2 * NT * DM;

    convert_qkv<<<dim3(4096, 1, 3), 256, 0, stream>>>(q, k, v, qb);
    transpose_w<<<dim3(16, 16, 4), 256, 0, stream>>>(Wq, Wk, Wv, Wp, wT);
    gemm_qkv   <<<dim3(8, 32, 3),  256, 0, stream>>>(qb, wT, bq, bk, bv, Qh);
    attn_kernel<<<dim3(512, 1),    256, 0, stream>>>(Qh, Kswz, Vswz, mask, attn, Ob);
    gemm_out   <<<dim3(8, 32),     256, 0, stream>>>(Ob, wT + 3*1048576, bp, q, out);
    ln_kernel  <<<4096,            256, 0, stream>>>(out, gamma, beta);
}